// Round 1
// baseline (232.419 us; speedup 1.0000x reference)
//
#include <hip/hip_runtime.h>
#include <stdint.h>

#define BB 4
#define TT 2048
#define DD 1024
#define NX (BB*TT*DD)          /* 8388608 x elements   */
#define NW (DD*DD)             /* 1048576 per W        */
#define SCALE 0.022097086912079608f   /* 1/sqrt(2048) */

typedef short v8s __attribute__((ext_vector_type(8)));
typedef float v4f __attribute__((ext_vector_type(4)));

typedef const void __attribute__((address_space(1))) *as1_cvp;
typedef void __attribute__((address_space(3))) *as3_vp;

__device__ __forceinline__ short f2bf(float f) {
    union { float f; uint32_t u; } x; x.f = f;
    uint32_t r = x.u + 0x7fffu + ((x.u >> 16) & 1u);   // RNE, finite inputs
    return (short)(r >> 16);
}
__device__ __forceinline__ float bf2f(short s) {
    union { uint32_t u; float f; } x; x.u = ((uint32_t)(uint16_t)s) << 16;
    return x.f;
}

// Async 16B global->LDS. lds dest must be wave-uniform base + lane*16.
__device__ __forceinline__ void gl_lds16(const short* g, const short* lds_wave_base) {
    __builtin_amdgcn_global_load_lds(
        (as1_cvp)(uintptr_t)(const void*)g,
        (as3_vp)(uint32_t)(uintptr_t)(const void*)lds_wave_base,
        16, 0, 0);
}

// ---- staging: rows x 64 shorts, XOR-8 chunk swizzle (row = 8 chunks = 32 banks)
__device__ __forceinline__ void stage_tile(const short* __restrict__ gsrc, int lda,
                                           short* lds, int tid) {     // 128 rows
    int wave = tid >> 6;
    #pragma unroll
    for (int is = 0; is < 4; is++) {
        int t = is * 256 + tid;          // 0..1023 : 16B chunk index
        int r = t >> 3, c = t & 7;
        int cg = c ^ (r & 7);            // swizzled global chunk
        const short* g = gsrc + (size_t)r * lda + cg * 8;
        const short* l = lds + is * 2048 + wave * 512;   // wave-uniform
        gl_lds16(g, l);
    }
}
__device__ __forceinline__ void stage_tile64(const short* __restrict__ gsrc, int lda,
                                             short* lds, int tid) {   // 64 rows
    int wave = tid >> 6;
    #pragma unroll
    for (int is = 0; is < 2; is++) {
        int t = is * 256 + tid;          // 0..511
        int r = t >> 3, c = t & 7;
        int cg = c ^ (r & 7);
        const short* g = gsrc + (size_t)r * lda + cg * 8;
        const short* l = lds + is * 2048 + wave * 512;
        gl_lds16(g, l);
    }
}
__device__ __forceinline__ v8s frag_read(const short* lds, int row, int cg) {
    return *(const v8s*)(lds + row * 64 + ((cg ^ (row & 7)) << 3));
}

// ---- 256-tile staging: part-mapped half-tiles (128 idx-rows x 64), 2 issues each.
// A part p holds global tile rows {wg*128 + p*64 + r : wg in {0,1}, r in 0..63}
//   -> idx = wg*64 + r  (read window: one segment for ALL waves)
__device__ __forceinline__ void stageA256(const short* __restrict__ g, short* lds,
                                          int tid, int p) {
    int wave = tid >> 6;
    #pragma unroll
    for (int s = 0; s < 2; s++) {
        int t = s * 512 + tid;           // 0..1023 : 16B chunk index
        int row = t >> 3, c = t & 7;
        int cg = c ^ (row & 7);
        int grow = ((row >> 6) << 7) + p * 64 + (row & 63);   // (row/64)*128 + p*64 + row%64
        gl_lds16(g + (size_t)grow * 1024 + cg * 8, lds + s * 4096 + wave * 512);
    }
}
// B part p holds global tile rows {ng*64 + p*32 + r : ng in 0..3, r in 0..31} -> idx = ng*32 + r
__device__ __forceinline__ void stageB256(const short* __restrict__ g, short* lds,
                                          int tid, int p) {
    int wave = tid >> 6;
    #pragma unroll
    for (int s = 0; s < 2; s++) {
        int t = s * 512 + tid;
        int row = t >> 3, c = t & 7;
        int cg = c ^ (row & 7);
        int grow = ((row >> 5) << 6) + p * 32 + (row & 31);   // (row/32)*64 + p*32 + row%32
        gl_lds16(g + (size_t)grow * 1024 + cg * 8, lds + s * 4096 + wave * 512);
    }
}

// 64x128 tile compute (4 waves 2x2 of 32x64), acc[2][4]  (k_pk / k_pv)
#define COMPUTE_TILE64(Ac, Bc)                                                      \
    _Pragma("unroll")                                                               \
    for (int kk = 0; kk < 2; kk++) {                                                \
        v8s af[2], bf[4];                                                           \
        _Pragma("unroll")                                                           \
        for (int i = 0; i < 2; i++) af[i] = frag_read(Ac, wm + i*16 + lr, kk*4 + lq); \
        _Pragma("unroll")                                                           \
        for (int j = 0; j < 4; j++) bf[j] = frag_read(Bc, wn + j*16 + lr, kk*4 + lq); \
        _Pragma("unroll")                                                           \
        for (int i = 0; i < 2; i++)                                                 \
            _Pragma("unroll")                                                       \
            for (int j = 0; j < 4; j++)                                             \
                acc[i][j] = __builtin_amdgcn_mfma_f32_16x16x32_bf16(af[i], bf[j], acc[i][j], 0, 0, 0); \
    }

// ---------------------------------------------------------------- convert (+ rowsum init)
__global__ void k_convert(const float* __restrict__ x, const float* __restrict__ Wq,
                          const float* __restrict__ Wk, const float* __restrict__ Wv,
                          short* __restrict__ dst, float* __restrict__ rowsum) {
    int i = blockIdx.x * 256 + threadIdx.x;   // exactly (NX+3*NW)/4 threads
    if (i < BB * TT) rowsum[i] = (float)((15 - ((i & 2047) >> 7)) * 128);
    size_t base = (size_t)i * 4;
    const float* src; size_t off;
    if (base < NX)               { src = x;  off = base; }
    else if (base < NX + NW)     { src = Wq; off = base - NX; }
    else if (base < NX + 2*(size_t)NW) { src = Wk; off = base - NX - NW; }
    else                         { src = Wv; off = base - NX - 2*(size_t)NW; }
    float4 f = *(const float4*)(src + off);
    short4 h; h.x = f2bf(f.x); h.y = f2bf(f.y); h.z = f2bf(f.z); h.w = f2bf(f.w);
    *(short4*)(dst + base) = h;
}

// ---------------------------------------------------------------- QKV GEMM
// 256x256 tile, BK=64, 8 waves (2M x 4N), counted-vmcnt 3-segment pipeline.
// LDS: 2 slots x (A[2 parts x 128x64] | B[2 parts x 128x64]) = 128 KB.
// Per K-tile t (slot c=t&1), staging tile t+1 into slot c^1:
//   SEG1 (Mlo,Nlo): read A1(t),B1(t); issue A1(t+1); 16 MFMA; vmcnt(4); bar
//   SEG2 (Mlo,Nhi): read B2(t);       issue B1(t+1); 16 MFMA; vmcnt(4); bar
//   SEG3 (Mhi,*):   read A2(t);       issue B2,A2(t+1); 32 MFMA; vmcnt(4); bar
// In-flight <= 8 loads; every region's staging issue is after the prev tenant's
// read-segment barrier; every deadline is covered by a counted wait. Never vmcnt(0)
// in the main loop (T3+T4); setprio around MFMA clusters (T5).
__global__ __launch_bounds__(512, 2) void k_qkv(const short* __restrict__ xb,
                                                const short* __restrict__ wb,
                                                short* __restrict__ q,
                                                short* __restrict__ k,
                                                short* __restrict__ vt) {
    int h = blockIdx.x;
    int w = (h & 7) * 48 + (h >> 3);          // bijective XCD swizzle (384 % 8 == 0)
    int which = w >> 7, rw = w & 127, ntile = rw >> 5, mtile = rw & 31;
    int m0 = mtile * 256, n0 = ntile * 256;
    const short* Ag = xb + (size_t)m0 * 1024;
    const short* Bg = wb + (size_t)which * NW + (size_t)n0 * 1024;
    __shared__ __align__(16) short SH[65536];   // 128 KB
    int tid = threadIdx.x, lane = tid & 63, wave = tid >> 6;
    int wm = (wave >> 2) * 128, wn = (wave & 3) * 64;
    int lr = lane & 15, lq = lane >> 4;
    int ar = (wm >> 1) + lr;                  // A part-local row base (0 or 64)
    int br = (wn >> 1) + lr;                  // B part-local row base (0/32/64/96)
    v4f acc[8][4];
    #pragma unroll
    for (int i = 0; i < 8; i++)
        #pragma unroll
        for (int j = 0; j < 4; j++) acc[i][j] = (v4f){0.f, 0.f, 0.f, 0.f};

    // prologue: tile 0, issue order A1,B1,B2,A2 so vmcnt(4) lands A1+B1
    stageA256(Ag, SH,                tid, 0);
    stageB256(Bg, SH + 16384,        tid, 0);
    stageB256(Bg, SH + 16384 + 8192, tid, 1);
    stageA256(Ag, SH + 8192,         tid, 1);
    asm volatile("s_waitcnt vmcnt(4)" ::: "memory");
    __builtin_amdgcn_s_barrier();

    for (int t = 0; t < 15; ++t) {
        short* sAc = SH + (t & 1) * 32768;
        short* sBc = sAc + 16384;
        short* sAn = SH + ((t & 1) ^ 1) * 32768;
        short* sBn = sAn + 16384;
        const short* Agn = Ag + (t + 1) * 64;
        const short* Bgn = Bg + (t + 1) * 64;
        v8s af[4][2], bf1[2][2], bf2[2][2];
        // ---------------- SEG1: (Mlo,Nlo)
        #pragma unroll
        for (int i = 0; i < 4; i++)
            #pragma unroll
            for (int kk = 0; kk < 2; kk++) af[i][kk] = frag_read(sAc, ar + i * 16, kk * 4 + lq);
        #pragma unroll
        for (int j = 0; j < 2; j++)
            #pragma unroll
            for (int kk = 0; kk < 2; kk++) bf1[j][kk] = frag_read(sBc, br + j * 16, kk * 4 + lq);
        stageA256(Agn, sAn, tid, 0);
        __builtin_amdgcn_s_setprio(1);
        #pragma unroll
        for (int kk = 0; kk < 2; kk++)
            #pragma unroll
            for (int i = 0; i < 4; i++)
                #pragma unroll
                for (int j = 0; j < 2; j++)
                    acc[i][j] = __builtin_amdgcn_mfma_f32_16x16x32_bf16(af[i][kk], bf1[j][kk], acc[i][j], 0, 0, 0);
        __builtin_amdgcn_s_setprio(0);
        asm volatile("s_waitcnt vmcnt(4)" ::: "memory");
        __builtin_amdgcn_s_barrier();
        // ---------------- SEG2: (Mlo,Nhi)
        #pragma unroll
        for (int j = 0; j < 2; j++)
            #pragma unroll
            for (int kk = 0; kk < 2; kk++) bf2[j][kk] = frag_read(sBc + 8192, br + j * 16, kk * 4 + lq);
        stageB256(Bgn, sBn, tid, 0);
        __builtin_amdgcn_s_setprio(1);
        #pragma unroll
        for (int kk = 0; kk < 2; kk++)
            #pragma unroll
            for (int i = 0; i < 4; i++)
                #pragma unroll
                for (int j = 0; j < 2; j++)
                    acc[i][2 + j] = __builtin_amdgcn_mfma_f32_16x16x32_bf16(af[i][kk], bf2[j][kk], acc[i][2 + j], 0, 0, 0);
        __builtin_amdgcn_s_setprio(0);
        asm volatile("s_waitcnt vmcnt(4)" ::: "memory");
        __builtin_amdgcn_s_barrier();
        // ---------------- SEG3: (Mhi,Nlo) + (Mhi,Nhi)
        #pragma unroll
        for (int i = 0; i < 4; i++)
            #pragma unroll
            for (int kk = 0; kk < 2; kk++) af[i][kk] = frag_read(sAc + 8192, ar + i * 16, kk * 4 + lq);
        stageB256(Bgn, sBn + 8192, tid, 1);
        __builtin_amdgcn_s_setprio(1);
        #pragma unroll
        for (int kk = 0; kk < 2; kk++)
            #pragma unroll
            for (int i = 0; i < 4; i++)
                #pragma unroll
                for (int j = 0; j < 2; j++)
                    acc[4 + i][j] = __builtin_amdgcn_mfma_f32_16x16x32_bf16(af[i][kk], bf1[j][kk], acc[4 + i][j], 0, 0, 0);
        __builtin_amdgcn_s_setprio(0);
        stageA256(Agn, sAn + 8192, tid, 1);
        __builtin_amdgcn_s_setprio(1);
        #pragma unroll
        for (int kk = 0; kk < 2; kk++)
            #pragma unroll
            for (int i = 0; i < 4; i++)
                #pragma unroll
                for (int j = 0; j < 2; j++)
                    acc[4 + i][2 + j] = __builtin_amdgcn_mfma_f32_16x16x32_bf16(af[i][kk], bf2[j][kk], acc[4 + i][2 + j], 0, 0, 0);
        __builtin_amdgcn_s_setprio(0);
        asm volatile("s_waitcnt vmcnt(4)" ::: "memory");
        __builtin_amdgcn_s_barrier();
    }
    // ---------------- tail: t = 15 (slot 1), no staging; drain remaining loads
    {
        short* sAc = SH + 32768;
        short* sBc = sAc + 16384;
        v8s af[4][2], bf1[2][2], bf2[2][2];
        #pragma unroll
        for (int i = 0; i < 4; i++)
            #pragma unroll
            for (int kk = 0; kk < 2; kk++) af[i][kk] = frag_read(sAc, ar + i * 16, kk * 4 + lq);
        #pragma unroll
        for (int j = 0; j < 2; j++)
            #pragma unroll
            for (int kk = 0; kk < 2; kk++) bf1[j][kk] = frag_read(sBc, br + j * 16, kk * 4 + lq);
        __builtin_amdgcn_s_setprio(1);
        #pragma unroll
        for (int kk = 0; kk < 2; kk++)
            #pragma unroll
            for (int i = 0; i < 4; i++)
                #pragma unroll
                for (int j = 0; j < 2; j++)
                    acc[i][j] = __builtin_amdgcn_mfma_f32_16x16x32_bf16(af[i][kk], bf1[j][kk], acc[i][j], 0, 0, 0);
        __builtin_amdgcn_s_setprio(0);
        asm volatile("s_waitcnt vmcnt(2)" ::: "memory");   // B2(15) landed
        __builtin_amdgcn_s_barrier();
        #pragma unroll
        for (int j = 0; j < 2; j++)
            #pragma unroll
            for (int kk = 0; kk < 2; kk++) bf2[j][kk] = frag_read(sBc + 8192, br + j * 16, kk * 4 + lq);
        __builtin_amdgcn_s_setprio(1);
        #pragma unroll
        for (int kk = 0; kk < 2; kk++)
            #pragma unroll
            for (int i = 0; i < 4; i++)
                #pragma unroll
                for (int j = 0; j < 2; j++)
                    acc[i][2 + j] = __builtin_amdgcn_mfma_f32_16x16x32_bf16(af[i][kk], bf2[j][kk], acc[i][2 + j], 0, 0, 0);
        __builtin_amdgcn_s_setprio(0);
        asm volatile("s_waitcnt vmcnt(0)" ::: "memory");   // A2(15) landed
        __builtin_amdgcn_s_barrier();
        #pragma unroll
        for (int i = 0; i < 4; i++)
            #pragma unroll
            for (int kk = 0; kk < 2; kk++) af[i][kk] = frag_read(sAc + 8192, ar + i * 16, kk * 4 + lq);
        __builtin_amdgcn_s_setprio(1);
        #pragma unroll
        for (int kk = 0; kk < 2; kk++)
            #pragma unroll
            for (int i = 0; i < 4; i++)
                #pragma unroll
                for (int j = 0; j < 2; j++) {
                    acc[4 + i][j]     = __builtin_amdgcn_mfma_f32_16x16x32_bf16(af[i][kk], bf1[j][kk], acc[4 + i][j], 0, 0, 0);
                    acc[4 + i][2 + j] = __builtin_amdgcn_mfma_f32_16x16x32_bf16(af[i][kk], bf2[j][kk], acc[4 + i][2 + j], 0, 0, 0);
                }
        __builtin_amdgcn_s_setprio(0);
    }
    // ---------------- epilogue
    if (which == 2) {
        #pragma unroll
        for (int a = 0; a < 8; a++)
            #pragma unroll
            for (int b = 0; b < 4; b++)
                #pragma unroll
                for (int r = 0; r < 4; r++) {
                    int row = m0 + wm + a * 16 + lq * 4 + r;   // m = bb*2048 + t
                    int col = n0 + wn + b * 16 + lr;           // e
                    int bb = row >> 11, tt2 = row & 2047;
                    vt[((size_t)bb << 21) + ((size_t)col << 11) + tt2] = f2bf(acc[a][b][r]);
                }
    } else {
        short* outp = (which == 0) ? q : k;
        #pragma unroll
        for (int a = 0; a < 8; a++)
            #pragma unroll
            for (int b = 0; b < 4; b++)
                #pragma unroll
                for (int r = 0; r < 4; r++) {
                    int row = m0 + wm + a * 16 + lq * 4 + r;
                    int col = n0 + wn + b * 16 + lr;
                    outp[(size_t)row * 1024 + col] = f2bf(acc[a][b][r]);
                }
    }
}

// ---------------------------------------------------------------- tile suffix sums
__global__ void k_ts1(const short* __restrict__ vt, float* __restrict__ TSpart) {
    int g = blockIdx.x * 256 + threadIdx.x;           // 4*16*1024 threads
    int b = g >> 14, jt = (g >> 10) & 15, e = g & 1023;
    const short* row = vt + ((size_t)b << 21) + ((size_t)e << 11) + jt * 128;
    float s = 0.f;
    #pragma unroll
    for (int c = 0; c < 16; c++) {
        uint4 u = *(const uint4*)(row + c * 8);
        const short* hp = (const short*)&u;
        #pragma unroll
        for (int z = 0; z < 8; z++) s += bf2f(hp[z]);
    }
    TSpart[g] = s;   // [b][jt][e]
}
__global__ void k_ts2(const float* __restrict__ TSpart, float* __restrict__ TS) {
    int g = blockIdx.x * 256 + threadIdx.x;           // 4*1024 threads
    int b = g >> 10, e = g & 1023;
    float acc = 0.f;
    TS[(size_t)(b * 17 + 16) * 1024 + e] = 0.f;
    for (int jt = 15; jt >= 0; jt--) {
        acc += TSpart[(size_t)(b * 16 + jt) * 1024 + e];
        TS[(size_t)(b * 17 + jt) * 1024 + e] = acc;   // sum over j >= jt*128
    }
}

// ---------------------------------------------------------------- S -> P kernel (BM=64, dbuf, FULL UNROLL)
// grid.x = 272 (136 triangular pairs x 2 halves), big-qt first
__global__ __launch_bounds__(256, 3) void k_pk(const short* __restrict__ qm,
                                               const short* __restrict__ km,
                                               short* __restrict__ P,
                                               float* __restrict__ rowsum) {
    int flip = 271 - blockIdx.x, b = blockIdx.z;
    int half = flip & 1, pidx = flip >> 1;
    int qt = 0;
    while ((qt + 1) * (qt + 2) / 2 <= pidx) qt++;
    int kt = pidx - qt * (qt + 1) / 2;
    int r0 = qt * 128 + half * 64;                       // first q-row of this block
    const short* Ag = qm + ((size_t)b * 2048 + r0) * 1024;            // 64 rows
    const short* Bg = km + ((size_t)b * 2048 + (size_t)kt * 128) * 1024; // 128 rows
    __shared__ __align__(16) short SH[24576];            // A dbuf 2x8KB | B dbuf 2x16KB
    int tid = threadIdx.x, lane = tid & 63, wave = tid >> 6;
    int wm = (wave >> 1) * 32, wn = (wave & 1) * 64;
    int lr = lane & 15, lq = lane >> 4;
    v4f acc[2][4];
    for (int i = 0; i < 2; i++) for (int j = 0; j < 4; j++) acc[i][j] = (v4f){0.f,0.f,0.f,0.f};

    stage_tile64(Ag, 1024, SH, tid);
    stage_tile(Bg, 1024, SH + 8192, tid);
    #pragma unroll
    for (int it = 0; it < 16; ++it) {
        __syncthreads();
        short* Ac = SH + (it & 1) * 4096;
        short* Bc = SH + 8192 + (it & 1) * 8192;
        if (it + 1 < 16) {
            stage_tile64(Ag + (it + 1) * 64, 1024, SH + ((it + 1) & 1) * 4096, tid);
            stage_tile  (Bg + (it + 1) * 64, 1024, SH + 8192 + ((it + 1) & 1) * 8192, tid);
        }
        COMPUTE_TILE64(Ac, Bc);
    }
    short* Pb = P + ((size_t)b << 22);
    float rs[2][4];
    for (int i = 0; i < 2; i++) for (int r = 0; r < 4; r++) rs[i][r] = 0.f;
    #pragma unroll
    for (int i = 0; i < 2; i++)
        #pragma unroll
        for (int j = 0; j < 4; j++)
            #pragma unroll
            for (int r = 0; r < 4; r++) {
                int qi = r0 + wm + i*16 + lq*4 + r;
                int kj = kt * 128 + wn + j*16 + lr;
                float p = (kj <= qi) ? __expf(acc[i][j][r] * SCALE) : 1.0f;
                Pb[(size_t)qi * 2048 + kj] = f2bf(p);
                rs[i][r] += p;
            }
    #pragma unroll
    for (int m = 1; m < 16; m <<= 1)
        #pragma unroll
        for (int i = 0; i < 2; i++)
            #pragma unroll
            for (int r = 0; r < 4; r++) rs[i][r] += __shfl_xor(rs[i][r], m);
    if (lr == 0)
        #pragma unroll
        for (int i = 0; i < 2; i++)
            #pragma unroll
            for (int r = 0; r < 4; r++)
                atomicAdd(&rowsum[b * 2048 + r0 + wm + i*16 + lq*4 + r], rs[i][r]);
}

// ---------------------------------------------------------------- PV kernel (BM=64, paired qt, 34 iters, UNROLL 2)
// grid = (8 et, 16 = 8 pairs x 2 halves, 4 b): 512 uniform blocks
__global__ __launch_bounds__(256, 3) void k_pv(const short* __restrict__ P,
                                               const short* __restrict__ vt,
                                               const float* __restrict__ rowsum,
                                               const float* __restrict__ TS,
                                               float* __restrict__ out) {
    int et = blockIdx.x, p = blockIdx.y >> 1, half = blockIdx.y & 1, b = blockIdx.z;
    const short* Bg = vt + ((size_t)b << 21) + (size_t)et * 128 * 2048;  // 128 e-rows, ld 2048
    __shared__ __align__(16) short SH[24576];            // A dbuf 2x8KB | B dbuf 2x16KB
    int tid = threadIdx.x, lane = tid & 63, wave = tid >> 6;
    int wm = (wave >> 1) * 32, wn = (wave & 1) * 64;
    int lr = lane & 15, lq = lane >> 4;

    #pragma unroll
    for (int ph = 0; ph < 2; ph++) {
        int qt = ph ? p : 15 - p;              // iters: 2(16-p) + 2(p+1) = 34 for all blocks
        int r0 = qt * 128 + half * 64;
        int iters = 2 * (qt + 1);              // always even
        const short* Ag = P + ((size_t)b << 22) + (size_t)r0 * 2048;   // 64 rows, ld 2048
        v4f acc[2][4];
        for (int i = 0; i < 2; i++) for (int j = 0; j < 4; j++) acc[i][j] = (v4f){0.f,0.f,0.f,0.f};

        stage_tile64(Ag, 2048, SH, tid);
        stage_tile(Bg, 2048, SH + 8192, tid);
        for (int it = 0; it < iters; it += 2) {
            // ---- even sub-iter: buffers 0, prefetch into buffers 1
            __syncthreads();
            if (it + 1 < iters) {
                stage_tile64(Ag + (it + 1) * 64, 2048, SH + 4096, tid);
                stage_tile  (Bg + (it + 1) * 64, 2048, SH + 8192 + 8192, tid);
            }
            COMPUTE_TILE64(SH, SH + 8192);
            // ---- odd sub-iter: buffers 1, prefetch into buffers 0
            __syncthreads();
            if (it + 2 < iters) {
                stage_tile64(Ag + (it + 2) * 64, 2048, SH, tid);
                stage_tile  (Bg + (it + 2) * 64, 2048, SH + 8192, tid);
            }
            COMPUTE_TILE64(SH + 4096, SH + 8192 + 8192);
        }
        const float* tsrow = TS + (size_t)(b * 17 + qt + 1) * 1024;
        #pragma unroll
        for (int i = 0; i < 2; i++)
            #pragma unroll
            for (int j = 0; j < 4; j++)
                #pragma unroll
                for (int r = 0; r < 4; r++) {
                    int row = r0 + wm + i*16 + lq*4 + r;
                    int col = et * 128 + wn + j*16 + lr;
                    float o = (acc[i][j][r] + tsrow[col]) / rowsum[b * 2048 + row];
                    out[((size_t)(b * 2048 + row) << 10) + col] = o;
                }
        __syncthreads();   // protect LDS before next phase's initial staging
    }
}

// ---------------------------------------------------------------- launch
extern "C" void kernel_launch(void* const* d_in, const int* in_sizes, int n_in,
                              void* d_out, int out_size, void* d_ws, size_t ws_size,
                              hipStream_t stream) {
    const float* x  = (const float*)d_in[0];
    const float* Wq = (const float*)d_in[1];
    const float* Wk = (const float*)d_in[2];
    const float* Wv = (const float*)d_in[3];
    float* out = (float*)d_out;
    char* ws = (char*)d_ws;

    short* xb     = (short*)(ws + 0);            // 16,777,216 B
    short* wb     = (short*)(ws + 16777216);     //  6,291,456 B (Wq|Wk|Wv bf16)
    short* q      = (short*)(ws + 23068672);     // 16,777,216 B
    short* k      = (short*)(ws + 39845888);     // 16,777,216 B
    short* vt     = (short*)(ws + 56623104);     // 16,777,216 B  v transposed [b][e][t]
    short* P      = (short*)(ws + 73400320);     // 33,554,432 B
    float* rowsum = (float*)(ws + 106954752);    //     32,768 B
    float* TSpart = (float*)(ws + 106987520);    //    262,144 B
    float* TS     = (float*)(ws + 107249664);    //    278,528 B   total ~102.6 MB

    k_convert<<<11264, 256, 0, stream>>>(x, Wq, Wk, Wv, xb, rowsum);
    k_qkv<<<dim3(384, 1, 1), 512, 0, stream>>>(xb, wb, q, k, vt);
    k_ts1<<<256, 256, 0, stream>>>(vt, TSpart);
    k_ts2<<<16, 256, 0, stream>>>(TSpart, TS);
    k_pk<<<dim3(272, 1, 4), 256, 0, stream>>>(q, k, P, rowsum);
    k_pv<<<dim3(8, 16, 4), 256, 0, stream>>>(P, vt, rowsum, TS, out);
}

// Round 2
// 224.825 us; speedup vs baseline: 1.0338x; 1.0338x over previous
//
#include <hip/hip_runtime.h>
#include <stdint.h>

#define BB 4
#define TT 2048
#define DD 1024
#define NX (BB*TT*DD)          /* 8388608 x elements   */
#define NW (DD*DD)             /* 1048576 per W        */
#define SCALE 0.022097086912079608f   /* 1/sqrt(2048) */

typedef short v8s __attribute__((ext_vector_type(8)));
typedef float v4f __attribute__((ext_vector_type(4)));

typedef const void __attribute__((address_space(1))) *as1_cvp;
typedef void __attribute__((address_space(3))) *as3_vp;

__device__ __forceinline__ short f2bf(float f) {
    union { float f; uint32_t u; } x; x.f = f;
    uint32_t r = x.u + 0x7fffu + ((x.u >> 16) & 1u);   // RNE, finite inputs
    return (short)(r >> 16);
}
__device__ __forceinline__ float bf2f(short s) {
    union { uint32_t u; float f; } x; x.u = ((uint32_t)(uint16_t)s) << 16;
    return x.f;
}

// Async 16B global->LDS. lds dest must be wave-uniform base + lane*16.
__device__ __forceinline__ void gl_lds16(const short* g, const short* lds_wave_base) {
    __builtin_amdgcn_global_load_lds(
        (as1_cvp)(uintptr_t)(const void*)g,
        (as3_vp)(uint32_t)(uintptr_t)(const void*)lds_wave_base,
        16, 0, 0);
}

// ---- staging: rows x 64 shorts, XOR-8 chunk swizzle (row = 8 chunks = 32 banks)
__device__ __forceinline__ void stage_tile(const short* __restrict__ gsrc, int lda,
                                           short* lds, int tid) {     // 128 rows, 256 thr
    int wave = tid >> 6;
    #pragma unroll
    for (int is = 0; is < 4; is++) {
        int t = is * 256 + tid;          // 0..1023 : 16B chunk index
        int r = t >> 3, c = t & 7;
        int cg = c ^ (r & 7);            // swizzled global chunk
        const short* g = gsrc + (size_t)r * lda + cg * 8;
        const short* l = lds + is * 2048 + wave * 512;   // wave-uniform
        gl_lds16(g, l);
    }
}
__device__ __forceinline__ void stage_tile64(const short* __restrict__ gsrc, int lda,
                                             short* lds, int tid) {   // 64 rows, 256 thr
    int wave = tid >> 6;
    #pragma unroll
    for (int is = 0; is < 2; is++) {
        int t = is * 256 + tid;          // 0..511
        int r = t >> 3, c = t & 7;
        int cg = c ^ (r & 7);
        const short* g = gsrc + (size_t)r * lda + cg * 8;
        const short* l = lds + is * 2048 + wave * 512;
        gl_lds16(g, l);
    }
}
__device__ __forceinline__ v8s frag_read(const short* lds, int row, int cg) {
    return *(const v8s*)(lds + row * 64 + ((cg ^ (row & 7)) << 3));
}

// ---- 512-thread staging helpers for k_qkv (row ld = 1024 shorts)
// A: 128 consecutive rows x 64 shorts (16 KB), 2 issues/wave
__device__ __forceinline__ void stageA128(const short* __restrict__ g, short* lds, int tid) {
    int wave = tid >> 6;
    #pragma unroll
    for (int s = 0; s < 2; s++) {
        int t = s * 512 + tid;           // 0..1023
        int r = t >> 3, c = t & 7;
        int cg = c ^ (r & 7);
        gl_lds16(g + (size_t)r * 1024 + cg * 8, lds + s * 4096 + wave * 512);
    }
}
// B part p: idx-row = wn*32 + r  holds global n-row wn*64 + p*32 + r  (16 KB), 2 issues
__device__ __forceinline__ void stageBpart(const short* __restrict__ g, short* lds,
                                           int tid, int p) {
    int wave = tid >> 6;
    #pragma unroll
    for (int s = 0; s < 2; s++) {
        int t = s * 512 + tid;
        int r = t >> 3, c = t & 7;
        int cg = c ^ (r & 7);
        int grow = ((r >> 5) << 6) + p * 32 + (r & 31);
        gl_lds16(g + (size_t)grow * 1024 + cg * 8, lds + s * 4096 + wave * 512);
    }
}

// 64x128 tile compute (4 waves 2x2 of 32x64), acc[2][4]  (k_pk / k_pv)
#define COMPUTE_TILE64(Ac, Bc)                                                      \
    _Pragma("unroll")                                                               \
    for (int kk = 0; kk < 2; kk++) {                                                \
        v8s af[2], bf[4];                                                           \
        _Pragma("unroll")                                                           \
        for (int i = 0; i < 2; i++) af[i] = frag_read(Ac, wm + i*16 + lr, kk*4 + lq); \
        _Pragma("unroll")                                                           \
        for (int j = 0; j < 4; j++) bf[j] = frag_read(Bc, wn + j*16 + lr, kk*4 + lq); \
        _Pragma("unroll")                                                           \
        for (int i = 0; i < 2; i++)                                                 \
            _Pragma("unroll")                                                       \
            for (int j = 0; j < 4; j++)                                             \
                acc[i][j] = __builtin_amdgcn_mfma_f32_16x16x32_bf16(af[i], bf[j], acc[i][j], 0, 0, 0); \
    }

// ---------------------------------------------------------------- convert (+ rowsum init)
__global__ void k_convert(const float* __restrict__ x, const float* __restrict__ Wq,
                          const float* __restrict__ Wk, const float* __restrict__ Wv,
                          short* __restrict__ dst, float* __restrict__ rowsum) {
    int i = blockIdx.x * 256 + threadIdx.x;   // exactly (NX+3*NW)/4 threads
    if (i < BB * TT) rowsum[i] = (float)((15 - ((i & 2047) >> 7)) * 128);
    size_t base = (size_t)i * 4;
    const float* src; size_t off;
    if (base < NX)               { src = x;  off = base; }
    else if (base < NX + NW)     { src = Wq; off = base - NX; }
    else if (base < NX + 2*(size_t)NW) { src = Wk; off = base - NX - NW; }
    else                         { src = Wv; off = base - NX - 2*(size_t)NW; }
    float4 f = *(const float4*)(src + off);
    short4 h; h.x = f2bf(f.x); h.y = f2bf(f.y); h.z = f2bf(f.z); h.w = f2bf(f.w);
    *(short4*)(dst + base) = h;
}

// ---------------------------------------------------------------- QKV GEMM
// BM=128, BN=256, BK=64, 8 waves (2M x 4N, per-wave 64x64), 768 blocks = 3 exact rounds.
// LDS 96 KB: 2 slots x (A 16K | Bpart0 16K | Bpart1 16K) -> 1 block/CU.
// Per K-tile: 2 phases of 16 MFMA/wave. Counted waits (never 0 in loop):
//   P1 start: vmcnt(2)  [A(t),Bp0(t) landed; Bp1(t) may fly]
//   P2 start: vmcnt(4)  [Bp1(t) landed; A,Bp0(t+1) may fly]
// Issue->wait distance = one full phase (~600 cyc MFMA) covers L2/L3 latency.
// In-flight ledger: <= 6 per wave; oldest-first completion (m135).
__global__ __launch_bounds__(512, 2) void k_qkv(const short* __restrict__ xb,
                                                const short* __restrict__ wb,
                                                short* __restrict__ q,
                                                short* __restrict__ k,
                                                short* __restrict__ vt) {
    int h = blockIdx.x;
    int w = (h & 7) * 96 + (h >> 3);          // bijective XCD swizzle (768 = 8*96)
    int which = w >> 8, rem = w & 255, ntile = rem >> 6, mtile = rem & 63;
    int m0 = mtile * 128, n0 = ntile * 256;
    const short* Ag = xb + (size_t)m0 * 1024;
    const short* Bg = wb + (size_t)which * NW + (size_t)n0 * 1024;
    __shared__ __align__(16) short SH[49152];   // 96 KB
    int tid = threadIdx.x, lane = tid & 63, wave = tid >> 6;
    int wm = wave >> 2, wn = wave & 3;          // 2M x 4N
    int lr = lane & 15, lq = lane >> 4;
    int arow = wm * 64 + lr;                    // + i*16
    int brow = wn * 32 + lr;                    // + jj*16 (part-local idx-row)
    v4f acc[4][4];
    #pragma unroll
    for (int i = 0; i < 4; i++)
        #pragma unroll
        for (int j = 0; j < 4; j++) acc[i][j] = (v4f){0.f, 0.f, 0.f, 0.f};

    // prologue: tile 0 into slot 0 (order A, Bp0, Bp1 so vmcnt(2) lands A+Bp0)
    stageA128 (Ag, SH,         tid);
    stageBpart(Bg, SH + 8192,  tid, 0);
    stageBpart(Bg, SH + 16384, tid, 1);

    #pragma unroll
    for (int t = 0; t < 16; ++t) {
        short* S  = SH + (t & 1) * 24576;
        short* Sn = SH + ((t + 1) & 1) * 24576;
        const short* Agn = Ag + (t + 1) * 64;
        const short* Bgn = Bg + (t + 1) * 64;
        // ---------------- phase 1: acc[*][0..1]  (A + B part0)
        asm volatile("s_waitcnt vmcnt(2)" ::: "memory");
        __builtin_amdgcn_s_barrier();
        v8s af[4][2], bf[2][2];
        #pragma unroll
        for (int i = 0; i < 4; i++)
            #pragma unroll
            for (int kk = 0; kk < 2; kk++) af[i][kk] = frag_read(S, arow + i * 16, kk * 4 + lq);
        #pragma unroll
        for (int jj = 0; jj < 2; jj++)
            #pragma unroll
            for (int kk = 0; kk < 2; kk++) bf[jj][kk] = frag_read(S + 8192, brow + jj * 16, kk * 4 + lq);
        if (t < 15) {
            stageA128 (Agn, Sn,        tid);
            stageBpart(Bgn, Sn + 8192, tid, 0);
        }
        __builtin_amdgcn_s_setprio(1);
        #pragma unroll
        for (int kk = 0; kk < 2; kk++)
            #pragma unroll
            for (int i = 0; i < 4; i++)
                #pragma unroll
                for (int jj = 0; jj < 2; jj++)
                    acc[i][jj] = __builtin_amdgcn_mfma_f32_16x16x32_bf16(af[i][kk], bf[jj][kk], acc[i][jj], 0, 0, 0);
        __builtin_amdgcn_s_setprio(0);
        // ---------------- phase 2: acc[*][2..3]  (B part1)
        if (t < 15) { asm volatile("s_waitcnt vmcnt(4)" ::: "memory"); }
        else        { asm volatile("s_waitcnt vmcnt(0)" ::: "memory"); }
        __builtin_amdgcn_s_barrier();
        v8s bg2[2][2];
        #pragma unroll
        for (int jj = 0; jj < 2; jj++)
            #pragma unroll
            for (int kk = 0; kk < 2; kk++) bg2[jj][kk] = frag_read(S + 16384, brow + jj * 16, kk * 4 + lq);
        if (t < 15) stageBpart(Bgn, Sn + 16384, tid, 1);
        __builtin_amdgcn_s_setprio(1);
        #pragma unroll
        for (int kk = 0; kk < 2; kk++)
            #pragma unroll
            for (int i = 0; i < 4; i++)
                #pragma unroll
                for (int jj = 0; jj < 2; jj++)
                    acc[i][2 + jj] = __builtin_amdgcn_mfma_f32_16x16x32_bf16(af[i][kk], bg2[jj][kk], acc[i][2 + jj], 0, 0, 0);
        __builtin_amdgcn_s_setprio(0);
    }

    // ---------------- epilogue
    if (which == 2) {
        #pragma unroll
        for (int a = 0; a < 4; a++)
            #pragma unroll
            for (int b = 0; b < 4; b++)
                #pragma unroll
                for (int r = 0; r < 4; r++) {
                    int row = m0 + wm * 64 + a * 16 + lq * 4 + r;   // m = bb*2048 + t
                    int col = n0 + wn * 64 + b * 16 + lr;           // e
                    int bb = row >> 11, tt2 = row & 2047;
                    vt[((size_t)bb << 21) + ((size_t)col << 11) + tt2] = f2bf(acc[a][b][r]);
                }
    } else {
        short* outp = (which == 0) ? q : k;
        #pragma unroll
        for (int a = 0; a < 4; a++)
            #pragma unroll
            for (int b = 0; b < 4; b++)
                #pragma unroll
                for (int r = 0; r < 4; r++) {
                    int row = m0 + wm * 64 + a * 16 + lq * 4 + r;
                    int col = n0 + wn * 64 + b * 16 + lr;
                    outp[(size_t)row * 1024 + col] = f2bf(acc[a][b][r]);
                }
    }
}

// ---------------------------------------------------------------- tile suffix sums
__global__ void k_ts1(const short* __restrict__ vt, float* __restrict__ TSpart) {
    int g = blockIdx.x * 256 + threadIdx.x;           // 4*16*1024 threads
    int b = g >> 14, jt = (g >> 10) & 15, e = g & 1023;
    const short* row = vt + ((size_t)b << 21) + ((size_t)e << 11) + jt * 128;
    float s = 0.f;
    #pragma unroll
    for (int c = 0; c < 16; c++) {
        uint4 u = *(const uint4*)(row + c * 8);
        const short* hp = (const short*)&u;
        #pragma unroll
        for (int z = 0; z < 8; z++) s += bf2f(hp[z]);
    }
    TSpart[g] = s;   // [b][jt][e]
}
__global__ void k_ts2(const float* __restrict__ TSpart, float* __restrict__ TS) {
    int g = blockIdx.x * 256 + threadIdx.x;           // 4*1024 threads
    int b = g >> 10, e = g & 1023;
    float acc = 0.f;
    TS[(size_t)(b * 17 + 16) * 1024 + e] = 0.f;
    for (int jt = 15; jt >= 0; jt--) {
        acc += TSpart[(size_t)(b * 16 + jt) * 1024 + e];
        TS[(size_t)(b * 17 + jt) * 1024 + e] = acc;   // sum over j >= jt*128
    }
}

// ---------------------------------------------------------------- S -> P kernel (BM=64, dbuf, FULL UNROLL)
// grid.x = 272 (136 triangular pairs x 2 halves), big-qt first
__global__ __launch_bounds__(256, 3) void k_pk(const short* __restrict__ qm,
                                               const short* __restrict__ km,
                                               short* __restrict__ P,
                                               float* __restrict__ rowsum) {
    int flip = 271 - blockIdx.x, b = blockIdx.z;
    int half = flip & 1, pidx = flip >> 1;
    int qt = 0;
    while ((qt + 1) * (qt + 2) / 2 <= pidx) qt++;
    int kt = pidx - qt * (qt + 1) / 2;
    int r0 = qt * 128 + half * 64;                       // first q-row of this block
    const short* Ag = qm + ((size_t)b * 2048 + r0) * 1024;            // 64 rows
    const short* Bg = km + ((size_t)b * 2048 + (size_t)kt * 128) * 1024; // 128 rows
    __shared__ __align__(16) short SH[24576];            // A dbuf 2x8KB | B dbuf 2x16KB
    int tid = threadIdx.x, lane = tid & 63, wave = tid >> 6;
    int wm = (wave >> 1) * 32, wn = (wave & 1) * 64;
    int lr = lane & 15, lq = lane >> 4;
    v4f acc[2][4];
    for (int i = 0; i < 2; i++) for (int j = 0; j < 4; j++) acc[i][j] = (v4f){0.f,0.f,0.f,0.f};

    stage_tile64(Ag, 1024, SH, tid);
    stage_tile(Bg, 1024, SH + 8192, tid);
    #pragma unroll
    for (int it = 0; it < 16; ++it) {
        __syncthreads();
        short* Ac = SH + (it & 1) * 4096;
        short* Bc = SH + 8192 + (it & 1) * 8192;
        if (it + 1 < 16) {
            stage_tile64(Ag + (it + 1) * 64, 1024, SH + ((it + 1) & 1) * 4096, tid);
            stage_tile  (Bg + (it + 1) * 64, 1024, SH + 8192 + ((it + 1) & 1) * 8192, tid);
        }
        COMPUTE_TILE64(Ac, Bc);
    }
    short* Pb = P + ((size_t)b << 22);
    float rs[2][4];
    for (int i = 0; i < 2; i++) for (int r = 0; r < 4; r++) rs[i][r] = 0.f;
    #pragma unroll
    for (int i = 0; i < 2; i++)
        #pragma unroll
        for (int j = 0; j < 4; j++)
            #pragma unroll
            for (int r = 0; r < 4; r++) {
                int qi = r0 + wm + i*16 + lq*4 + r;
                int kj = kt * 128 + wn + j*16 + lr;
                float p = (kj <= qi) ? __expf(acc[i][j][r] * SCALE) : 1.0f;
                Pb[(size_t)qi * 2048 + kj] = f2bf(p);
                rs[i][r] += p;
            }
    #pragma unroll
    for (int m = 1; m < 16; m <<= 1)
        #pragma unroll
        for (int i = 0; i < 2; i++)
            #pragma unroll
            for (int r = 0; r < 4; r++) rs[i][r] += __shfl_xor(rs[i][r], m);
    if (lr == 0)
        #pragma unroll
        for (int i = 0; i < 2; i++)
            #pragma unroll
            for (int r = 0; r < 4; r++)
                atomicAdd(&rowsum[b * 2048 + r0 + wm + i*16 + lq*4 + r], rs[i][r]);
}

// ---------------------------------------------------------------- PV kernel (BM=64, paired qt, 34 iters, UNROLL 2)
// grid = (8 et, 16 = 8 pairs x 2 halves, 4 b): 512 uniform blocks
__global__ __launch_bounds__(256, 3) void k_pv(const short* __restrict__ P,
                                               const short* __restrict__ vt,
                                               const float* __restrict__ rowsum,
                                               const float* __restrict__ TS,
                                               float* __restrict__ out) {
    int et = blockIdx.x, p = blockIdx.y >> 1, half = blockIdx.y & 1, b = blockIdx.z;
    const short* Bg = vt + ((size_t)b << 21) + (size_t)et * 128 * 2048;  // 128 e-rows, ld 2048
    __shared__ __align__(16) short SH[24576];            // A dbuf 2x8KB | B dbuf 2x16KB
    int tid = threadIdx.x, lane = tid & 63, wave = tid >> 6;
    int wm = (wave >> 1) * 32, wn = (wave & 1) * 64;
    int lr = lane & 15, lq = lane >> 4;

    #pragma unroll
    for (int ph = 0; ph < 2; ph++) {
        int qt = ph ? p : 15 - p;              // iters: 2(16-p) + 2(p+1) = 34 for all blocks
        int r0 = qt * 128 + half * 64;
        int iters = 2 * (qt + 1);              // always even
        const short* Ag = P + ((size_t)b << 22) + (size_t)r0 * 2048;   // 64 rows, ld 2048
        v4f acc[2][4];
        for (int i = 0; i < 2; i++) for (int j = 0; j < 4; j++) acc[i][j] = (v4f){0.f,0.f,0.f,0.f};

        stage_tile64(Ag, 2048, SH, tid);
        stage_tile(Bg, 2048, SH + 8192, tid);
        for (int it = 0; it < iters; it += 2) {
            // ---- even sub-iter: buffers 0, prefetch into buffers 1
            __syncthreads();
            if (it + 1 < iters) {
                stage_tile64(Ag + (it + 1) * 64, 2048, SH + 4096, tid);
                stage_tile  (Bg + (it + 1) * 64, 2048, SH + 8192 + 8192, tid);
            }
            COMPUTE_TILE64(SH, SH + 8192);
            // ---- odd sub-iter: buffers 1, prefetch into buffers 0
            __syncthreads();
            if (it + 2 < iters) {
                stage_tile64(Ag + (it + 2) * 64, 2048, SH, tid);
                stage_tile  (Bg + (it + 2) * 64, 2048, SH + 8192, tid);
            }
            COMPUTE_TILE64(SH + 4096, SH + 8192 + 8192);
        }
        const float* tsrow = TS + (size_t)(b * 17 + qt + 1) * 1024;
        #pragma unroll
        for (int i = 0; i < 2; i++)
            #pragma unroll
            for (int j = 0; j < 4; j++)
                #pragma unroll
                for (int r = 0; r < 4; r++) {
                    int row = r0 + wm + i*16 + lq*4 + r;
                    int col = et * 128 + wn + j*16 + lr;
                    float o = (acc[i][j][r] + tsrow[col]) / rowsum[b * 2048 + row];
                    out[((size_t)(b * 2048 + row) << 10) + col] = o;
                }
        __syncthreads();   // protect LDS before next phase's initial staging
    }
}

// ---------------------------------------------------------------- launch
extern "C" void kernel_launch(void* const* d_in, const int* in_sizes, int n_in,
                              void* d_out, int out_size, void* d_ws, size_t ws_size,
                              hipStream_t stream) {
    const float* x  = (const float*)d_in[0];
    const float* Wq = (const float*)d_in[1];
    const float* Wk = (const float*)d_in[2];
    const float* Wv = (const float*)d_in[3];
    float* out = (float*)d_out;
    char* ws = (char*)d_ws;

    short* xb     = (short*)(ws + 0);            // 16,777,216 B
    short* wb     = (short*)(ws + 16777216);     //  6,291,456 B (Wq|Wk|Wv bf16)
    short* q      = (short*)(ws + 23068672);     // 16,777,216 B
    short* k      = (short*)(ws + 39845888);     // 16,777,216 B
    short* vt     = (short*)(ws + 56623104);     // 16,777,216 B  v transposed [b][e][t]
    short* P      = (short*)(ws + 73400320);     // 33,554,432 B
    float* rowsum = (float*)(ws + 106954752);    //     32,768 B
    float* TSpart = (float*)(ws + 106987520);    //    262,144 B
    float* TS     = (float*)(ws + 107249664);    //    278,528 B   total ~102.6 MB

    k_convert<<<11264, 256, 0, stream>>>(x, Wq, Wk, Wv, xb, rowsum);
    k_qkv<<<dim3(768, 1, 1), 512, 0, stream>>>(xb, wb, q, k, vt);
    k_ts1<<<256, 256, 0, stream>>>(vt, TSpart);
    k_ts2<<<16, 256, 0, stream>>>(TSpart, TS);
    k_pk<<<dim3(272, 1, 4), 256, 0, stream>>>(q, k, P, rowsum);
    k_pv<<<dim3(8, 16, 4), 256, 0, stream>>>(P, vt, rowsum, TS, out);
}